// Round 1
// baseline (3797.502 us; speedup 1.0000x reference)
//
#include <hip/hip_runtime.h>

#define NM 1200
#define PP 719400      // NM*(NM-1)/2
#define HID 128
#define RANK 64
#define SDP_ITERS 100

// ---------------- ws layout (floats) ----------------
// S[48*48]=2304 | xsum[48] @2304 | sumw2 @2352 | cvec[128] @2368 |
// W1s[40*128] @2496 | w[PP(+pad)] @7616 | W[1200*1200] @727040 |
// Va @2167040 | Vb @2243840 | end 2320640 floats (~9.3 MB)
#define OFF_S      0
#define OFF_XSUM   2304
#define OFF_SUMW2  2352
#define OFF_CVEC   2368
#define OFF_W1S    2496
#define OFF_WVEC   7616
#define OFF_WMAT   727040
#define OFF_VA     2167040
#define OFF_VB     2243840

__device__ __forceinline__ float wave_reduce_sum(float v) {
#pragma unroll
    for (int o = 32; o > 0; o >>= 1) v += __shfl_xor(v, o, 64);
    return v;
}

__global__ __launch_bounds__(256) void zero_kernel(float* __restrict__ ws, int n) {
    int i = blockIdx.x * 256 + threadIdx.x;
    if (i < n) ws[i] = 0.0f;
}

// ---- pass 1: S = x^T x (48x48 padded), xsum = column sums ----
#define STATS_BLOCKS 600
#define STATS_CHUNK  1199   // 600*1199 == PP exactly
__global__ __launch_bounds__(256) void stats_kernel(const float* __restrict__ x,
                                                    float* __restrict__ S,
                                                    float* __restrict__ xsum) {
    __shared__ float tile[64 * 48];
    const int k0 = blockIdx.x * STATS_CHUNK;
    const int k1 = k0 + STATS_CHUNK;   // == min(..., PP) since it divides evenly
    const int ty = threadIdx.x >> 4, tx = threadIdx.x & 15;
    float acc[3][3] = {{0.f,0.f,0.f},{0.f,0.f,0.f},{0.f,0.f,0.f}};
    float cs[3] = {0.f, 0.f, 0.f};

    for (int t = k0; t < k1; t += 64) {
        const int nrows = min(64, k1 - t);
        __syncthreads();
        for (int idx = threadIdx.x; idx < 64 * 48; idx += 256) {
            int r = idx / 48, c = idx - r * 48;
            float v = 0.f;
            if (r < nrows && c < 39) v = x[(size_t)(t + r) * 39 + c];
            tile[idx] = v;
        }
        __syncthreads();
        for (int k = 0; k < 64; ++k) {
            const float* row = &tile[k * 48];
            float a0 = row[ty], a1 = row[ty + 16], a2 = row[ty + 32];
            float b0 = row[tx], b1 = row[tx + 16], b2 = row[tx + 32];
            acc[0][0] = fmaf(a0, b0, acc[0][0]);
            acc[0][1] = fmaf(a0, b1, acc[0][1]);
            acc[0][2] = fmaf(a0, b2, acc[0][2]);
            acc[1][0] = fmaf(a1, b0, acc[1][0]);
            acc[1][1] = fmaf(a1, b1, acc[1][1]);
            acc[1][2] = fmaf(a1, b2, acc[1][2]);
            acc[2][0] = fmaf(a2, b0, acc[2][0]);
            acc[2][1] = fmaf(a2, b1, acc[2][1]);
            acc[2][2] = fmaf(a2, b2, acc[2][2]);
            if (ty == 0) { cs[0] += b0; cs[1] += b1; cs[2] += b2; }
        }
    }
#pragma unroll
    for (int q = 0; q < 3; ++q)
#pragma unroll
        for (int u = 0; u < 3; ++u)
            atomicAdd(&S[(ty + 16 * q) * 48 + tx + 16 * u], acc[q][u]);
    if (ty == 0) {
#pragma unroll
        for (int u = 0; u < 3; ++u) atomicAdd(&xsum[tx + 16 * u], cs[u]);
    }
}

// ---- BN folding: W1s[:,j] = W1[:,j]*scale_j ; cvec[j] = -s1_j*scale_j + beta_j ----
__global__ __launch_bounds__(64) void bn_prep(const float* __restrict__ S,
                                              const float* __restrict__ xsum,
                                              const float* __restrict__ W1,
                                              const float* __restrict__ b1,
                                              const float* __restrict__ gamma,
                                              const float* __restrict__ beta,
                                              float* __restrict__ W1s,
                                              float* __restrict__ cvec) {
    const int j = blockIdx.x;
    const int l = threadIdx.x;
    const float invP = 1.0f / (float)PP;
    float q = 0.f;
    for (int idx = l; idx < 39 * 39; idx += 64) {
        int a = idx / 39, b = idx - a * 39;
        q = fmaf(S[a * 48 + b], W1[a * HID + j] * W1[b * HID + j], q);
    }
    float s1 = (l < 39) ? (xsum[l] * invP) * W1[l * HID + j] : 0.f;
    q = wave_reduce_sum(q);
    s1 = wave_reduce_sum(s1);
    float var = q * invP - s1 * s1;
    float scale = gamma[j] * (1.0f / sqrtf(var + 1e-5f));
    for (int a = l; a < 39; a += 64) W1s[a * HID + j] = W1[a * HID + j] * scale;
    if (l == 0) cvec[j] = -s1 * scale + beta[j];
}

// ---- fused MLP: w[p] = relu(x.W1s + cvec) . W2 + b2 ; also sum w^2 ----
__global__ __launch_bounds__(256) void mlp_kernel(const float* __restrict__ x,
                                                  const float* __restrict__ W1s,
                                                  const float* __restrict__ cvec,
                                                  const float* __restrict__ W2,
                                                  const float* __restrict__ b2,
                                                  float* __restrict__ w,
                                                  float* __restrict__ sumw2) {
    __shared__ float xt[256 * 39];
    __shared__ float red[4];
    const size_t base = (size_t)blockIdx.x * 256;
    {
        const size_t g0 = base * 39;
        const size_t gmax = (size_t)PP * 39;
        for (int idx = threadIdx.x; idx < 256 * 39; idx += 256) {
            size_t g = g0 + idx;
            xt[idx] = (g < gmax) ? x[g] : 0.f;
        }
    }
    __syncthreads();
    float xr[39];
#pragma unroll
    for (int k = 0; k < 39; ++k) xr[k] = xt[threadIdx.x * 39 + k];

    float wacc = 0.f;
#pragma unroll
    for (int c = 0; c < 4; ++c) {
        float acc[32];
#pragma unroll
        for (int jj = 0; jj < 32; ++jj) acc[jj] = cvec[c * 32 + jj];
        for (int k = 0; k < 39; ++k) {
            const float xk = xr[k];
            const float* wrow = &W1s[k * HID + c * 32];
#pragma unroll
            for (int jj = 0; jj < 32; ++jj) acc[jj] = fmaf(xk, wrow[jj], acc[jj]);
        }
#pragma unroll
        for (int jj = 0; jj < 32; ++jj) {
            float v = fmaxf(acc[jj], 0.f);
            wacc = fmaf(v, W2[c * 32 + jj], wacc);
        }
    }
    const size_t p = base + threadIdx.x;
    const float wv = wacc + b2[0];
    float sq = 0.f;
    if (p < (size_t)PP) { w[p] = wv; sq = wv * wv; }
    sq = wave_reduce_sum(sq);
    if ((threadIdx.x & 63) == 0) red[threadIdx.x >> 6] = sq;
    __syncthreads();
    if (threadIdx.x == 0) atomicAdd(sumw2, red[0] + red[1] + red[2] + red[3]);
}

// ---- W[i,j] = (i==j) ? 0 : w[triu_index(min,max)] ----
__global__ __launch_bounds__(256) void buildW(const float* __restrict__ w,
                                              float* __restrict__ W) {
    const int j = blockIdx.x * 16 + threadIdx.x;
    const int i = blockIdx.y * 16 + threadIdx.y;
    float v = 0.f;
    if (i != j) {
        int a = min(i, j), b = max(i, j);
        // p = a*(N-1) - a*(a-1)/2 + (b - a - 1)
        int p = a * (NM - 1) - (a * (a - 1)) / 2 + (b - a - 1);
        v = w[p];
    }
    W[i * NM + j] = v;
}

// ---- V = V0 / ||row|| ----
__global__ __launch_bounds__(256) void v0norm(const float* __restrict__ V0,
                                              float* __restrict__ V) {
    const int i = blockIdx.x * 4 + (threadIdx.x >> 6);
    const int c = threadIdx.x & 63;
    float v = V0[(size_t)i * RANK + c];
    float s = wave_reduce_sum(v * v);
    V[(size_t)i * RANK + c] = v * (1.0f / sqrtf(s));
}

// ---- one SDP step: Vout = rownorm(Vin + lr * W @ Vin) ----
// 300 blocks x 256 threads; block handles 4 output rows; wave w covers K-quarter.
__global__ __launch_bounds__(256) void sdp_step(const float* __restrict__ Vin,
                                                float* __restrict__ Vout,
                                                const float* __restrict__ W,
                                                const float* __restrict__ sumw2) {
    __shared__ float part[4 * 4 * 64];   // [wave][row][lane]
    const int wv = threadIdx.x >> 6;
    const int c = threadIdx.x & 63;
    const int i0 = blockIdx.x * 4;
    const float lr = 1.0f / (sqrtf(2.0f * sumw2[0]) + 1e-8f);

    float acc0 = 0.f, acc1 = 0.f, acc2 = 0.f, acc3 = 0.f;
    const int j0 = wv * 300;
    const float* Wr = &W[(size_t)i0 * NM];
    for (int j = j0; j < j0 + 300; ++j) {
        const float vv = Vin[(size_t)j * RANK + c];
        acc0 = fmaf(Wr[j], vv, acc0);
        acc1 = fmaf(Wr[NM + j], vv, acc1);
        acc2 = fmaf(Wr[2 * NM + j], vv, acc2);
        acc3 = fmaf(Wr[3 * NM + j], vv, acc3);
    }
    part[(wv * 4 + 0) * 64 + c] = acc0;
    part[(wv * 4 + 1) * 64 + c] = acc1;
    part[(wv * 4 + 2) * 64 + c] = acc2;
    part[(wv * 4 + 3) * 64 + c] = acc3;
    __syncthreads();
    const int r = wv;   // wave r finalizes row i0+r
    float y = Vin[(size_t)(i0 + r) * RANK + c] +
              lr * (part[(0 * 4 + r) * 64 + c] + part[(1 * 4 + r) * 64 + c] +
                    part[(2 * 4 + r) * 64 + c] + part[(3 * 4 + r) * 64 + c]);
    float s = wave_reduce_sum(y * y);
    Vout[(size_t)(i0 + r) * RANK + c] = y * (1.0f / sqrtf(s));
}

// ---- out = clip(V V^T, 0, 1) ----
__global__ __launch_bounds__(256) void vvt_kernel(const float* __restrict__ V,
                                                  float* __restrict__ out) {
    __shared__ float Vi[64][65];
    __shared__ float Vj[64][65];
    const int i0 = blockIdx.y * 64, j0 = blockIdx.x * 64;
    for (int idx = threadIdx.x; idx < 64 * 64; idx += 256) {
        int r = idx >> 6, k = idx & 63;
        Vi[r][k] = (i0 + r < NM) ? V[(size_t)(i0 + r) * RANK + k] : 0.f;
        Vj[r][k] = (j0 + r < NM) ? V[(size_t)(j0 + r) * RANK + k] : 0.f;
    }
    __syncthreads();
    const int ty = threadIdx.x >> 4, tx = threadIdx.x & 15;
    float acc[4][4];
#pragma unroll
    for (int q = 0; q < 4; ++q)
#pragma unroll
        for (int u = 0; u < 4; ++u) acc[q][u] = 0.f;
    for (int k = 0; k < 64; ++k) {
        float a0 = Vi[4 * ty + 0][k], a1 = Vi[4 * ty + 1][k];
        float a2 = Vi[4 * ty + 2][k], a3 = Vi[4 * ty + 3][k];
        float b0 = Vj[4 * tx + 0][k], b1 = Vj[4 * tx + 1][k];
        float b2 = Vj[4 * tx + 2][k], b3 = Vj[4 * tx + 3][k];
        acc[0][0] = fmaf(a0, b0, acc[0][0]); acc[0][1] = fmaf(a0, b1, acc[0][1]);
        acc[0][2] = fmaf(a0, b2, acc[0][2]); acc[0][3] = fmaf(a0, b3, acc[0][3]);
        acc[1][0] = fmaf(a1, b0, acc[1][0]); acc[1][1] = fmaf(a1, b1, acc[1][1]);
        acc[1][2] = fmaf(a1, b2, acc[1][2]); acc[1][3] = fmaf(a1, b3, acc[1][3]);
        acc[2][0] = fmaf(a2, b0, acc[2][0]); acc[2][1] = fmaf(a2, b1, acc[2][1]);
        acc[2][2] = fmaf(a2, b2, acc[2][2]); acc[2][3] = fmaf(a2, b3, acc[2][3]);
        acc[3][0] = fmaf(a3, b0, acc[3][0]); acc[3][1] = fmaf(a3, b1, acc[3][1]);
        acc[3][2] = fmaf(a3, b2, acc[3][2]); acc[3][3] = fmaf(a3, b3, acc[3][3]);
    }
#pragma unroll
    for (int q = 0; q < 4; ++q) {
        int i = i0 + 4 * ty + q;
        if (i >= NM) continue;
#pragma unroll
        for (int u = 0; u < 4; ++u) {
            int j = j0 + 4 * tx + u;
            if (j < NM) out[(size_t)i * NM + j] = fminf(fmaxf(acc[q][u], 0.f), 1.f);
        }
    }
}

extern "C" void kernel_launch(void* const* d_in, const int* in_sizes, int n_in,
                              void* d_out, int out_size, void* d_ws, size_t ws_size,
                              hipStream_t stream) {
    const float* x     = (const float*)d_in[0];
    const float* W1    = (const float*)d_in[1];
    const float* b1    = (const float*)d_in[2];
    const float* gamma = (const float*)d_in[3];
    const float* beta  = (const float*)d_in[4];
    const float* W2    = (const float*)d_in[5];
    const float* b2    = (const float*)d_in[6];
    const float* V0    = (const float*)d_in[7];
    float* out = (float*)d_out;

    float* ws    = (float*)d_ws;
    float* S     = ws + OFF_S;
    float* xsum  = ws + OFF_XSUM;
    float* sumw2 = ws + OFF_SUMW2;
    float* cvec  = ws + OFF_CVEC;
    float* W1s   = ws + OFF_W1S;
    float* wvec  = ws + OFF_WVEC;
    float* Wmat  = ws + OFF_WMAT;
    float* Va    = ws + OFF_VA;
    float* Vb    = ws + OFF_VB;

    zero_kernel<<<10, 256, 0, stream>>>(ws, OFF_W1S);
    stats_kernel<<<STATS_BLOCKS, 256, 0, stream>>>(x, S, xsum);
    bn_prep<<<HID, 64, 0, stream>>>(S, xsum, W1, b1, gamma, beta, W1s, cvec);
    mlp_kernel<<<(PP + 255) / 256, 256, 0, stream>>>(x, W1s, cvec, W2, b2, wvec, sumw2);
    buildW<<<dim3(NM / 16, NM / 16), dim3(16, 16), 0, stream>>>(wvec, Wmat);
    v0norm<<<NM / 4, 256, 0, stream>>>(V0, Va);
    for (int it = 0; it < SDP_ITERS; ++it) {
        const float* vin = (it & 1) ? Vb : Va;
        float* vout      = (it & 1) ? Va : Vb;
        sdp_step<<<NM / 4, 256, 0, stream>>>(vin, vout, Wmat, sumw2);
    }
    // after 100 iters the final V is in Va (iter 99 writes Va)
    vvt_kernel<<<dim3(19, 19), 256, 0, stream>>>(Va, out);
}

// Round 2
// 2242.945 us; speedup vs baseline: 1.6931x; 1.6931x over previous
//
#include <hip/hip_runtime.h>

#define NM 1200
#define PP 719400      // NM*(NM-1)/2
#define HID 128
#define RANK 64
#define SDP_ITERS 100

// ---------------- ws layout (floats) ----------------
// S[40*40]=1600 | sumw2 @1600 | cvec[128] @1664 | W1s[40*128] @1792 |
// w[PP] @6912 | W[1200*1200] @726400 | Va @2166400 | Vb @2243200 | end 2320000
#define OFF_S      0
#define OFF_SUMW2  1600
#define OFF_CVEC   1664
#define OFF_W1S    1792
#define OFF_WVEC   6912
#define OFF_WMAT   726400
#define OFF_VA     2166400
#define OFF_VB     2243200

__device__ __forceinline__ float wave_reduce_sum(float v) {
#pragma unroll
    for (int o = 32; o > 0; o >>= 1) v += __shfl_xor(v, o, 64);
    return v;
}

__global__ __launch_bounds__(256) void zero_kernel(float* __restrict__ ws, int n) {
    int i = blockIdx.x * 256 + threadIdx.x;
    if (i < n) ws[i] = 0.0f;
}

// ---- pass 1: S[40x40] = [x | 1]^T [x | 1] (ones in col 39 -> row 39 of S = colsums) ----
#define SROWS 32
#define STATS_BLOCKS 1024
__global__ __launch_bounds__(256) void stats_kernel(const float* __restrict__ x,
                                                    float* __restrict__ S) {
    __shared__ float tile[SROWS * 40];
    __shared__ float Sacc[1600];
    const int tid = threadIdx.x;
    for (int i = tid; i < 1600; i += 256) Sacc[i] = 0.f;

    const int rows_per_block = (PP + STATS_BLOCKS - 1) / STATS_BLOCKS;  // 703
    const int r0 = blockIdx.x * rows_per_block;
    const int r1 = min(r0 + rows_per_block, PP);

    const int ty = (tid >> 3) & 7, tx = tid & 7, z = tid >> 6;
    float acc[5][5];
#pragma unroll
    for (int q = 0; q < 5; ++q)
#pragma unroll
        for (int u = 0; u < 5; ++u) acc[q][u] = 0.f;

    for (int t = r0; t < r1; t += SROWS) {
        const int nr = min(SROWS, r1 - t);
        __syncthreads();
        for (int idx = tid; idx < SROWS * 40; idx += 256) {
            int rr = idx / 40, c = idx - rr * 40;
            float v = 0.f;
            if (rr < nr) v = (c < 39) ? x[(size_t)(t + rr) * 39 + c] : 1.0f;
            tile[idx] = v;
        }
        __syncthreads();
#pragma unroll 2
        for (int k0 = 0; k0 < SROWS; k0 += 4) {
            const float* row = &tile[(k0 + z) * 40];
            float a[5], b[5];
#pragma unroll
            for (int u = 0; u < 5; ++u) a[u] = row[ty * 5 + u];
#pragma unroll
            for (int u = 0; u < 5; ++u) b[u] = row[tx * 5 + u];
#pragma unroll
            for (int q = 0; q < 5; ++q)
#pragma unroll
                for (int u = 0; u < 5; ++u) acc[q][u] = fmaf(a[q], b[u], acc[q][u]);
        }
    }
#pragma unroll
    for (int q = 0; q < 5; ++q)
#pragma unroll
        for (int u = 0; u < 5; ++u)
            atomicAdd(&Sacc[(ty * 5 + q) * 40 + tx * 5 + u], acc[q][u]);
    __syncthreads();
    for (int i = tid; i < 1600; i += 256) atomicAdd(&S[i], Sacc[i]);
}

// ---- BN folding: W1s[:,j] = W1[:,j]*scale_j ; cvec[j] = -s1_j*scale_j + beta_j ----
__global__ __launch_bounds__(64) void bn_prep(const float* __restrict__ S,
                                              const float* __restrict__ W1,
                                              const float* __restrict__ gamma,
                                              const float* __restrict__ beta,
                                              float* __restrict__ W1s,
                                              float* __restrict__ cvec) {
    const int j = blockIdx.x;
    const int l = threadIdx.x;
    const float invP = 1.0f / (float)PP;
    float q = 0.f;
    for (int idx = l; idx < 39 * 39; idx += 64) {
        int a = idx / 39, b = idx - a * 39;
        q = fmaf(S[a * 40 + b], W1[a * HID + j] * W1[b * HID + j], q);
    }
    float s1 = (l < 39) ? (S[39 * 40 + l] * invP) * W1[l * HID + j] : 0.f;
    q = wave_reduce_sum(q);
    s1 = wave_reduce_sum(s1);
    float var = q * invP - s1 * s1;
    float scale = gamma[j] * (1.0f / sqrtf(var + 1e-5f));
    for (int a = l; a < 39; a += 64) W1s[a * HID + j] = W1[a * HID + j] * scale;
    if (l == 0) cvec[j] = -s1 * scale + beta[j];
}

// ---- fused MLP: w[p] = relu(x.W1s + cvec) . W2 + b2 ; also sum w^2 ----
__global__ __launch_bounds__(256) void mlp_kernel(const float* __restrict__ x,
                                                  const float* __restrict__ W1s,
                                                  const float* __restrict__ cvec,
                                                  const float* __restrict__ W2,
                                                  const float* __restrict__ b2,
                                                  float* __restrict__ w,
                                                  float* __restrict__ sumw2) {
    __shared__ float xt[256 * 39];
    __shared__ float red[4];
    const size_t base = (size_t)blockIdx.x * 256;
    {
        const size_t g0 = base * 39;
        const size_t gmax = (size_t)PP * 39;
        for (int idx = threadIdx.x; idx < 256 * 39; idx += 256) {
            size_t g = g0 + idx;
            xt[idx] = (g < gmax) ? x[g] : 0.f;
        }
    }
    __syncthreads();
    float xr[39];
#pragma unroll
    for (int k = 0; k < 39; ++k) xr[k] = xt[threadIdx.x * 39 + k];

    float wacc = 0.f;
#pragma unroll
    for (int c = 0; c < 4; ++c) {
        float acc[32];
#pragma unroll
        for (int jj = 0; jj < 32; ++jj) acc[jj] = cvec[c * 32 + jj];
        for (int k = 0; k < 39; ++k) {
            const float xk = xr[k];
            const float* wrow = &W1s[k * HID + c * 32];
#pragma unroll
            for (int jj = 0; jj < 32; ++jj) acc[jj] = fmaf(xk, wrow[jj], acc[jj]);
        }
#pragma unroll
        for (int jj = 0; jj < 32; ++jj) {
            float v = fmaxf(acc[jj], 0.f);
            wacc = fmaf(v, W2[c * 32 + jj], wacc);
        }
    }
    const size_t p = base + threadIdx.x;
    const float wv = wacc + b2[0];
    float sq = 0.f;
    if (p < (size_t)PP) { w[p] = wv; sq = wv * wv; }
    sq = wave_reduce_sum(sq);
    if ((threadIdx.x & 63) == 0) red[threadIdx.x >> 6] = sq;
    __syncthreads();
    if (threadIdx.x == 0) atomicAdd(sumw2, red[0] + red[1] + red[2] + red[3]);
}

// ---- W build: symmetric tiles, both writes coalesced via LDS transpose ----
__global__ __launch_bounds__(256) void buildW(const float* __restrict__ w,
                                              float* __restrict__ W) {
    __shared__ float tile[16][17];
    const int bi = blockIdx.y, bj = blockIdx.x;
    if (bi > bj) return;
    const int ty = threadIdx.x >> 4, tx = threadIdx.x & 15;
    const int i = bi * 16 + ty, j = bj * 16 + tx;
    float v = 0.f;
    if (i < j) {
        int p = i * (NM - 1) - (i * (i - 1)) / 2 + (j - i - 1);
        v = w[p];
    }
    tile[ty][tx] = v;
    __syncthreads();
    if (bi == bj) {
        float out = (i < j) ? v : ((i > j) ? tile[tx][ty] : 0.f);
        W[(size_t)i * NM + j] = out;
    } else {
        W[(size_t)i * NM + j] = v;
        W[(size_t)(bj * 16 + ty) * NM + (bi * 16 + tx)] = tile[tx][ty];
    }
}

// ---- V = V0 / ||row|| ----
__global__ __launch_bounds__(256) void v0norm(const float* __restrict__ V0,
                                              float* __restrict__ V) {
    const int i = blockIdx.x * 4 + (threadIdx.x >> 6);
    const int c = threadIdx.x & 63;
    float v = V0[(size_t)i * RANK + c];
    float s = wave_reduce_sum(v * v);
    V[(size_t)i * RANK + c] = v * (1.0f / sqrtf(s));
}

// ---- one SDP step: Vout = rownorm(Vin + lr * W @ Vin) ----
// 600 blocks x 256: block owns 2 rows; 8-way K split; thread owns float4 colgroup.
__global__ __launch_bounds__(256) void sdp_step(const float* __restrict__ Vin,
                                                float* __restrict__ Vout,
                                                const float* __restrict__ W,
                                                const float* __restrict__ sumw2) {
    __shared__ __align__(16) float part[16 * 64];   // [kq*2+r][c]
    const int tid = threadIdx.x;
    const int g  = tid & 15;          // colgroup (cols 4g..4g+3)
    const int r  = (tid >> 4) & 1;    // row within block
    const int kq = tid >> 5;          // 0..7, K chunk of 150
    const int i0 = blockIdx.x * 2;
    const float lr = 1.0f / (sqrtf(2.0f * sumw2[0]) + 1e-8f);
    const float4* __restrict__ V4 = (const float4*)Vin;

    const float* __restrict__ Wr = W + (size_t)(i0 + r) * NM + kq * 150;
    const float4* __restrict__ Vp = V4 + (size_t)(kq * 150) * 16 + g;
    float4 acc = {0.f, 0.f, 0.f, 0.f};
#pragma unroll 5
    for (int t = 0; t < 150; ++t) {
        const float wv = Wr[t];
        const float4 v = Vp[t * 16];
        acc.x = fmaf(wv, v.x, acc.x);
        acc.y = fmaf(wv, v.y, acc.y);
        acc.z = fmaf(wv, v.z, acc.z);
        acc.w = fmaf(wv, v.w, acc.w);
    }
    ((float4*)part)[(kq * 2 + r) * 16 + g] = acc;
    __syncthreads();
    if (tid < 128) {
        const int c = tid & 63, r2 = tid >> 6;
        float s = 0.f;
#pragma unroll
        for (int k2 = 0; k2 < 8; ++k2) s += part[(k2 * 2 + r2) * 64 + c];
        float y = Vin[(size_t)(i0 + r2) * RANK + c] + lr * s;
        float n = wave_reduce_sum(y * y);
        Vout[(size_t)(i0 + r2) * RANK + c] = y * (1.0f / sqrtf(n));
    }
}

// ---- out = clip(V V^T, 0, 1) ----
__global__ __launch_bounds__(256) void vvt_kernel(const float* __restrict__ V,
                                                  float* __restrict__ out) {
    __shared__ float Vi[64][65];
    __shared__ float Vj[64][65];
    const int i0 = blockIdx.y * 64, j0 = blockIdx.x * 64;
    for (int idx = threadIdx.x; idx < 64 * 64; idx += 256) {
        int r = idx >> 6, k = idx & 63;
        Vi[r][k] = (i0 + r < NM) ? V[(size_t)(i0 + r) * RANK + k] : 0.f;
        Vj[r][k] = (j0 + r < NM) ? V[(size_t)(j0 + r) * RANK + k] : 0.f;
    }
    __syncthreads();
    const int ty = threadIdx.x >> 4, tx = threadIdx.x & 15;
    float acc[4][4];
#pragma unroll
    for (int q = 0; q < 4; ++q)
#pragma unroll
        for (int u = 0; u < 4; ++u) acc[q][u] = 0.f;
    for (int k = 0; k < 64; ++k) {
        float a0 = Vi[4 * ty + 0][k], a1 = Vi[4 * ty + 1][k];
        float a2 = Vi[4 * ty + 2][k], a3 = Vi[4 * ty + 3][k];
        float b0 = Vj[4 * tx + 0][k], b1 = Vj[4 * tx + 1][k];
        float b2 = Vj[4 * tx + 2][k], b3 = Vj[4 * tx + 3][k];
        acc[0][0] = fmaf(a0, b0, acc[0][0]); acc[0][1] = fmaf(a0, b1, acc[0][1]);
        acc[0][2] = fmaf(a0, b2, acc[0][2]); acc[0][3] = fmaf(a0, b3, acc[0][3]);
        acc[1][0] = fmaf(a1, b0, acc[1][0]); acc[1][1] = fmaf(a1, b1, acc[1][1]);
        acc[1][2] = fmaf(a1, b2, acc[1][2]); acc[1][3] = fmaf(a1, b3, acc[1][3]);
        acc[2][0] = fmaf(a2, b0, acc[2][0]); acc[2][1] = fmaf(a2, b1, acc[2][1]);
        acc[2][2] = fmaf(a2, b2, acc[2][2]); acc[2][3] = fmaf(a2, b3, acc[2][3]);
        acc[3][0] = fmaf(a3, b0, acc[3][0]); acc[3][1] = fmaf(a3, b1, acc[3][1]);
        acc[3][2] = fmaf(a3, b2, acc[3][2]); acc[3][3] = fmaf(a3, b3, acc[3][3]);
    }
#pragma unroll
    for (int q = 0; q < 4; ++q) {
        int i = i0 + 4 * ty + q;
        if (i >= NM) continue;
#pragma unroll
        for (int u = 0; u < 4; ++u) {
            int j = j0 + 4 * tx + u;
            if (j < NM) out[(size_t)i * NM + j] = fminf(fmaxf(acc[q][u], 0.f), 1.f);
        }
    }
}

extern "C" void kernel_launch(void* const* d_in, const int* in_sizes, int n_in,
                              void* d_out, int out_size, void* d_ws, size_t ws_size,
                              hipStream_t stream) {
    const float* x     = (const float*)d_in[0];
    const float* W1    = (const float*)d_in[1];
    const float* gamma = (const float*)d_in[3];
    const float* beta  = (const float*)d_in[4];
    const float* W2    = (const float*)d_in[5];
    const float* b2    = (const float*)d_in[6];
    const float* V0    = (const float*)d_in[7];
    float* out = (float*)d_out;

    float* ws    = (float*)d_ws;
    float* S     = ws + OFF_S;
    float* sumw2 = ws + OFF_SUMW2;
    float* cvec  = ws + OFF_CVEC;
    float* W1s   = ws + OFF_W1S;
    float* wvec  = ws + OFF_WVEC;
    float* Wmat  = ws + OFF_WMAT;
    float* Va    = ws + OFF_VA;
    float* Vb    = ws + OFF_VB;

    zero_kernel<<<7, 256, 0, stream>>>(ws, OFF_W1S);   // S + sumw2 (+slack)
    stats_kernel<<<STATS_BLOCKS, 256, 0, stream>>>(x, S);
    bn_prep<<<HID, 64, 0, stream>>>(S, W1, gamma, beta, W1s, cvec);
    mlp_kernel<<<(PP + 255) / 256, 256, 0, stream>>>(x, W1s, cvec, W2, b2, wvec, sumw2);
    buildW<<<dim3(75, 75), 256, 0, stream>>>(wvec, Wmat);
    v0norm<<<NM / 4, 256, 0, stream>>>(V0, Va);
    for (int it = 0; it < SDP_ITERS; ++it) {
        const float* vin = (it & 1) ? Vb : Va;
        float* vout      = (it & 1) ? Va : Vb;
        sdp_step<<<NM / 2, 256, 0, stream>>>(vin, vout, Wmat, sumw2);
    }
    // iter 99 (odd) writes Va
    vvt_kernel<<<dim3(19, 19), 256, 0, stream>>>(Va, out);
}

// Round 3
// 1637.049 us; speedup vs baseline: 2.3197x; 1.3701x over previous
//
#include <hip/hip_runtime.h>

#define NM 1200
#define PP 719400      // NM*(NM-1)/2
#define HID 128
#define RANK 64
#define SDP_ITERS 100

// ---------------- ws layout (floats) ----------------
#define OFF_S      0
#define OFF_SUMW2  1600
#define OFF_CVEC   1664
#define OFF_W1S    1792
#define OFF_WVEC   6912
#define OFF_WMAT   726400
#define OFF_VA     2166400
#define OFF_VB     2243200

__device__ __forceinline__ float wave_reduce_sum(float v) {
#pragma unroll
    for (int o = 32; o > 0; o >>= 1) v += __shfl_xor(v, o, 64);
    return v;
}

__global__ __launch_bounds__(256) void zero_kernel(float* __restrict__ ws, int n) {
    int i = blockIdx.x * 256 + threadIdx.x;
    if (i < n) ws[i] = 0.0f;
}

// ---- pass 1: S[40x40] = [x | 1]^T [x | 1] (ones in col 39 -> row 39 of S = colsums) ----
#define SROWS 32
#define STATS_BLOCKS 1024
__global__ __launch_bounds__(256) void stats_kernel(const float* __restrict__ x,
                                                    float* __restrict__ S) {
    __shared__ float tile[SROWS * 40];
    __shared__ float Sacc[1600];
    const int tid = threadIdx.x;
    for (int i = tid; i < 1600; i += 256) Sacc[i] = 0.f;

    const int rows_per_block = (PP + STATS_BLOCKS - 1) / STATS_BLOCKS;  // 703
    const int r0 = blockIdx.x * rows_per_block;
    const int r1 = min(r0 + rows_per_block, PP);

    const int ty = (tid >> 3) & 7, tx = tid & 7, z = tid >> 6;
    float acc[5][5];
#pragma unroll
    for (int q = 0; q < 5; ++q)
#pragma unroll
        for (int u = 0; u < 5; ++u) acc[q][u] = 0.f;

    for (int t = r0; t < r1; t += SROWS) {
        const int nr = min(SROWS, r1 - t);
        __syncthreads();
        for (int idx = tid; idx < SROWS * 40; idx += 256) {
            int rr = idx / 40, c = idx - rr * 40;
            float v = 0.f;
            if (rr < nr) v = (c < 39) ? x[(size_t)(t + rr) * 39 + c] : 1.0f;
            tile[idx] = v;
        }
        __syncthreads();
#pragma unroll 2
        for (int k0 = 0; k0 < SROWS; k0 += 4) {
            const float* row = &tile[(k0 + z) * 40];
            float a[5], b[5];
#pragma unroll
            for (int u = 0; u < 5; ++u) a[u] = row[ty * 5 + u];
#pragma unroll
            for (int u = 0; u < 5; ++u) b[u] = row[tx * 5 + u];
#pragma unroll
            for (int q = 0; q < 5; ++q)
#pragma unroll
                for (int u = 0; u < 5; ++u) acc[q][u] = fmaf(a[q], b[u], acc[q][u]);
        }
    }
#pragma unroll
    for (int q = 0; q < 5; ++q)
#pragma unroll
        for (int u = 0; u < 5; ++u)
            atomicAdd(&Sacc[(ty * 5 + q) * 40 + tx * 5 + u], acc[q][u]);
    __syncthreads();
    for (int i = tid; i < 1600; i += 256) atomicAdd(&S[i], Sacc[i]);
}

// ---- BN folding ----
__global__ __launch_bounds__(64) void bn_prep(const float* __restrict__ S,
                                              const float* __restrict__ W1,
                                              const float* __restrict__ gamma,
                                              const float* __restrict__ beta,
                                              float* __restrict__ W1s,
                                              float* __restrict__ cvec) {
    const int j = blockIdx.x;
    const int l = threadIdx.x;
    const float invP = 1.0f / (float)PP;
    float q = 0.f;
    for (int idx = l; idx < 39 * 39; idx += 64) {
        int a = idx / 39, b = idx - a * 39;
        q = fmaf(S[a * 40 + b], W1[a * HID + j] * W1[b * HID + j], q);
    }
    float s1 = (l < 39) ? (S[39 * 40 + l] * invP) * W1[l * HID + j] : 0.f;
    q = wave_reduce_sum(q);
    s1 = wave_reduce_sum(s1);
    float var = q * invP - s1 * s1;
    float scale = gamma[j] * (1.0f / sqrtf(var + 1e-5f));
    for (int a = l; a < 39; a += 64) W1s[a * HID + j] = W1[a * HID + j] * scale;
    if (l == 0) cvec[j] = -s1 * scale + beta[j];
}

// ---- fused MLP: k-outer, 128 accumulators in VGPRs ----
__global__ __launch_bounds__(256, 3) void mlp_kernel(const float* __restrict__ x,
                                                     const float* __restrict__ W1s,
                                                     const float* __restrict__ cvec,
                                                     const float* __restrict__ W2,
                                                     const float* __restrict__ b2,
                                                     float* __restrict__ w,
                                                     float* __restrict__ sumw2) {
    __shared__ float xt[256 * 39];
    __shared__ float red[4];
    const size_t base = (size_t)blockIdx.x * 256;
    {
        const size_t g0 = base * 39;
        const size_t gmax = (size_t)PP * 39;
        for (int idx = threadIdx.x; idx < 256 * 39; idx += 256) {
            size_t g = g0 + idx;
            xt[idx] = (g < gmax) ? x[g] : 0.f;
        }
    }
    __syncthreads();

    float acc[128];
#pragma unroll
    for (int jj = 0; jj < 128; ++jj) acc[jj] = cvec[jj];

    const float* xrow = &xt[threadIdx.x * 39];
#pragma unroll 3
    for (int k = 0; k < 39; ++k) {
        const float xk = xrow[k];
        const float* wrow = &W1s[k * HID];
#pragma unroll
        for (int jj = 0; jj < 128; ++jj) acc[jj] = fmaf(xk, wrow[jj], acc[jj]);
    }

    float wacc = 0.f;
#pragma unroll
    for (int jj = 0; jj < 128; ++jj)
        wacc = fmaf(fmaxf(acc[jj], 0.f), W2[jj], wacc);

    const size_t p = base + threadIdx.x;
    const float wv = wacc + b2[0];
    float sq = 0.f;
    if (p < (size_t)PP) { w[p] = wv; sq = wv * wv; }
    sq = wave_reduce_sum(sq);
    if ((threadIdx.x & 63) == 0) red[threadIdx.x >> 6] = sq;
    __syncthreads();
    if (threadIdx.x == 0) atomicAdd(sumw2, red[0] + red[1] + red[2] + red[3]);
}

// ---- W build: symmetric tiles, both writes coalesced via LDS transpose ----
__global__ __launch_bounds__(256) void buildW(const float* __restrict__ w,
                                              float* __restrict__ W) {
    __shared__ float tile[16][17];
    const int bi = blockIdx.y, bj = blockIdx.x;
    if (bi > bj) return;
    const int ty = threadIdx.x >> 4, tx = threadIdx.x & 15;
    const int i = bi * 16 + ty, j = bj * 16 + tx;
    float v = 0.f;
    if (i < j) {
        int p = i * (NM - 1) - (i * (i - 1)) / 2 + (j - i - 1);
        v = w[p];
    }
    tile[ty][tx] = v;
    __syncthreads();
    if (bi == bj) {
        float out = (i < j) ? v : ((i > j) ? tile[tx][ty] : 0.f);
        W[(size_t)i * NM + j] = out;
    } else {
        W[(size_t)i * NM + j] = v;
        W[(size_t)(bj * 16 + ty) * NM + (bi * 16 + tx)] = tile[tx][ty];
    }
}

// ---- V = V0 / ||row|| ----
__global__ __launch_bounds__(256) void v0norm(const float* __restrict__ V0,
                                              float* __restrict__ V) {
    const int i = blockIdx.x * 4 + (threadIdx.x >> 6);
    const int c = threadIdx.x & 63;
    float v = V0[(size_t)i * RANK + c];
    float s = wave_reduce_sum(v * v);
    V[(size_t)i * RANK + c] = v * (1.0f / sqrtf(s));
}

// ---- one SDP step: Vout = rownorm(Vin + lr * W @ Vin) ----
// 150 blocks x 256 threads; 8 rows/block; thread = (g=col4-group, kq=K/16 chunk).
// W rows staged to LDS transposed (Wl[j][8] -> 2x ds_read_b128 per j);
// V read as coalesced float4, each j touched once per block (46 MB/iter total).
#define SDP_RPB 8
#define SDP_KQ 16
#define SDP_KLEN 75   // NM / SDP_KQ
__global__ __launch_bounds__(256) void sdp_step(const float* __restrict__ Vin,
                                                float* __restrict__ Vout,
                                                const float* __restrict__ W,
                                                const float* __restrict__ sumw2) {
    __shared__ __align__(16) float Wl[NM * SDP_RPB];                 // [j][r] 38.4 KB
    __shared__ __align__(16) float part[SDP_KQ * SDP_RPB * 64];      // 32 KB
    const int tid = threadIdx.x;
    const int i0 = blockIdx.x * SDP_RPB;

    for (int idx = tid; idx < NM * SDP_RPB; idx += 256) {
        int r = idx / NM, j = idx - r * NM;
        Wl[j * SDP_RPB + r] = W[(size_t)(i0 + r) * NM + j];
    }
    __syncthreads();

    const int g  = tid & 15;
    const int kq = tid >> 4;
    const float4* __restrict__ Vp = (const float4*)Vin + (size_t)(kq * SDP_KLEN) * 16 + g;
    const float* __restrict__ Wp = &Wl[kq * SDP_KLEN * SDP_RPB];

    float4 acc[SDP_RPB];
#pragma unroll
    for (int r = 0; r < SDP_RPB; ++r) acc[r] = make_float4(0.f, 0.f, 0.f, 0.f);

#pragma unroll 5
    for (int t = 0; t < SDP_KLEN; ++t) {
        const float4 v = Vp[t * 16];
        const float* wj = &Wp[t * SDP_RPB];
#pragma unroll
        for (int r = 0; r < SDP_RPB; ++r) {
            const float wv = wj[r];
            acc[r].x = fmaf(wv, v.x, acc[r].x);
            acc[r].y = fmaf(wv, v.y, acc[r].y);
            acc[r].z = fmaf(wv, v.z, acc[r].z);
            acc[r].w = fmaf(wv, v.w, acc[r].w);
        }
    }
    float4* p4 = (float4*)part;
#pragma unroll
    for (int r = 0; r < SDP_RPB; ++r) p4[(kq * SDP_RPB + r) * 16 + g] = acc[r];
    __syncthreads();

    const int c = tid & 63;
    const float lr = 1.0f / (sqrtf(2.0f * sumw2[0]) + 1e-8f);
#pragma unroll
    for (int h = 0; h < 2; ++h) {
        const int r = (tid >> 6) + h * 4;
        float s = 0.f;
#pragma unroll
        for (int k2 = 0; k2 < SDP_KQ; ++k2) s += part[(k2 * SDP_RPB + r) * 64 + c];
        float y = Vin[(size_t)(i0 + r) * RANK + c] + lr * s;
        float n = wave_reduce_sum(y * y);
        Vout[(size_t)(i0 + r) * RANK + c] = y * (1.0f / sqrtf(n));
    }
}

// ---- out = clip(V V^T, 0, 1) ----
__global__ __launch_bounds__(256) void vvt_kernel(const float* __restrict__ V,
                                                  float* __restrict__ out) {
    __shared__ float Vi[64][65];
    __shared__ float Vj[64][65];
    const int i0 = blockIdx.y * 64, j0 = blockIdx.x * 64;
    for (int idx = threadIdx.x; idx < 64 * 64; idx += 256) {
        int r = idx >> 6, k = idx & 63;
        Vi[r][k] = (i0 + r < NM) ? V[(size_t)(i0 + r) * RANK + k] : 0.f;
        Vj[r][k] = (j0 + r < NM) ? V[(size_t)(j0 + r) * RANK + k] : 0.f;
    }
    __syncthreads();
    const int ty = threadIdx.x >> 4, tx = threadIdx.x & 15;
    float acc[4][4];
#pragma unroll
    for (int q = 0; q < 4; ++q)
#pragma unroll
        for (int u = 0; u < 4; ++u) acc[q][u] = 0.f;
    for (int k = 0; k < 64; ++k) {
        float a0 = Vi[4 * ty + 0][k], a1 = Vi[4 * ty + 1][k];
        float a2 = Vi[4 * ty + 2][k], a3 = Vi[4 * ty + 3][k];
        float b0 = Vj[4 * tx + 0][k], b1 = Vj[4 * tx + 1][k];
        float b2 = Vj[4 * tx + 2][k], b3 = Vj[4 * tx + 3][k];
        acc[0][0] = fmaf(a0, b0, acc[0][0]); acc[0][1] = fmaf(a0, b1, acc[0][1]);
        acc[0][2] = fmaf(a0, b2, acc[0][2]); acc[0][3] = fmaf(a0, b3, acc[0][3]);
        acc[1][0] = fmaf(a1, b0, acc[1][0]); acc[1][1] = fmaf(a1, b1, acc[1][1]);
        acc[1][2] = fmaf(a1, b2, acc[1][2]); acc[1][3] = fmaf(a1, b3, acc[1][3]);
        acc[2][0] = fmaf(a2, b0, acc[2][0]); acc[2][1] = fmaf(a2, b1, acc[2][1]);
        acc[2][2] = fmaf(a2, b2, acc[2][2]); acc[2][3] = fmaf(a2, b3, acc[2][3]);
        acc[3][0] = fmaf(a3, b0, acc[3][0]); acc[3][1] = fmaf(a3, b1, acc[3][1]);
        acc[3][2] = fmaf(a3, b2, acc[3][2]); acc[3][3] = fmaf(a3, b3, acc[3][3]);
    }
#pragma unroll
    for (int q = 0; q < 4; ++q) {
        int i = i0 + 4 * ty + q;
        if (i >= NM) continue;
#pragma unroll
        for (int u = 0; u < 4; ++u) {
            int j = j0 + 4 * tx + u;
            if (j < NM) out[(size_t)i * NM + j] = fminf(fmaxf(acc[q][u], 0.f), 1.f);
        }
    }
}

extern "C" void kernel_launch(void* const* d_in, const int* in_sizes, int n_in,
                              void* d_out, int out_size, void* d_ws, size_t ws_size,
                              hipStream_t stream) {
    const float* x     = (const float*)d_in[0];
    const float* W1    = (const float*)d_in[1];
    const float* gamma = (const float*)d_in[3];
    const float* beta  = (const float*)d_in[4];
    const float* W2    = (const float*)d_in[5];
    const float* b2    = (const float*)d_in[6];
    const float* V0    = (const float*)d_in[7];
    float* out = (float*)d_out;

    float* ws    = (float*)d_ws;
    float* S     = ws + OFF_S;
    float* sumw2 = ws + OFF_SUMW2;
    float* cvec  = ws + OFF_CVEC;
    float* W1s   = ws + OFF_W1S;
    float* wvec  = ws + OFF_WVEC;
    float* Wmat  = ws + OFF_WMAT;
    float* Va    = ws + OFF_VA;
    float* Vb    = ws + OFF_VB;

    zero_kernel<<<7, 256, 0, stream>>>(ws, OFF_W1S);   // S + sumw2 (+slack)
    stats_kernel<<<STATS_BLOCKS, 256, 0, stream>>>(x, S);
    bn_prep<<<HID, 64, 0, stream>>>(S, W1, gamma, beta, W1s, cvec);
    mlp_kernel<<<(PP + 255) / 256, 256, 0, stream>>>(x, W1s, cvec, W2, b2, wvec, sumw2);
    buildW<<<dim3(75, 75), 256, 0, stream>>>(wvec, Wmat);
    v0norm<<<NM / 4, 256, 0, stream>>>(V0, Va);
    for (int it = 0; it < SDP_ITERS; ++it) {
        const float* vin = (it & 1) ? Vb : Va;
        float* vout      = (it & 1) ? Va : Vb;
        sdp_step<<<NM / SDP_RPB, 256, 0, stream>>>(vin, vout, Wmat, sumw2);
    }
    // iter 99 (odd) writes Va
    vvt_kernel<<<dim3(19, 19), 256, 0, stream>>>(Va, out);
}